// Round 1
// baseline (1103.230 us; speedup 1.0000x reference)
//
#include <hip/hip_runtime.h>
#include <hip/hip_bf16.h>
#include <math.h>

#define NEG 0.01f

__device__ __forceinline__ float lrelu(float x) { return x > 0.f ? x : NEG * x; }

// ---------------- CSR build ----------------
__global__ void k_zero(int* deg, int* cur, int n) {
    int i = blockIdx.x * blockDim.x + threadIdx.x;
    if (i < n) { deg[i] = 0; cur[i] = 0; }
}

__global__ void k_count(const int* dst, int* deg, int E) {
    int e = blockIdx.x * blockDim.x + threadIdx.x;
    if (e < E) atomicAdd(&deg[dst[e]], 1);
}

__global__ __launch_bounds__(1024) void k_scan(const int* deg, int* off, int n) {
    __shared__ int part[1024];
    int t = threadIdx.x;
    int chunk = (n + 1023) / 1024;
    int lo = t * chunk, hi = min(n, lo + chunk);
    int s = 0;
    for (int i = lo; i < hi; i++) s += deg[i];
    part[t] = s;
    __syncthreads();
    for (int d = 1; d < 1024; d <<= 1) {
        int v = (t >= d) ? part[t - d] : 0;
        __syncthreads();
        part[t] += v;
        __syncthreads();
    }
    int run = (t == 0) ? 0 : part[t - 1];
    for (int i = lo; i < hi; i++) { off[i] = run; run += deg[i]; }
    if (t == 0) off[n] = part[1023];
}

__global__ void k_fill(const int* src, const int* dst, const float* eattr,
                       const int* off, int* cur, int* src_perm, float* attr_perm, int E) {
    int e = blockIdx.x * blockDim.x + threadIdx.x;
    if (e >= E) return;
    int d = dst[e];
    int slot = off[d] + atomicAdd(&cur[d], 1);
    src_perm[slot] = src[e];
    float a[8];
#pragma unroll
    for (int k = 0; k < 7; k++) a[k] = eattr[e * 7 + k];
    a[7] = 0.f;
    float4* dst4 = (float4*)(attr_perm + (size_t)slot * 8);
    dst4[0] = make_float4(a[0], a[1], a[2], a[3]);
    dst4[1] = make_float4(a[4], a[5], a[6], a[7]);
}

// ---------------- embedding gather ----------------
__global__ void k_embed(const int* x, const float* emb, float* hcat, int N) {
    int idx = blockIdx.x * blockDim.x + threadIdx.x;
    int i = idx >> 6, j = idx & 63;
    if (i < N) hcat[(size_t)i * 256 + j] = emb[(size_t)x[i] * 64 + j];
}

// ---------------- per-layer: g = h @ W1a, r = h . att_r ----------------
__global__ __launch_bounds__(256) void k_prep(const float* hcat, int hoff,
                                              const float* w1a, const float* ar,
                                              float* g, float* r, int N) {
    __shared__ float sW[64 * 64];
    __shared__ float sh[4][64];
    int tid = threadIdx.x;
    {
        const float4* w4 = (const float4*)w1a;
        float4* s4 = (float4*)sW;
        for (int i = tid; i < 1024; i += 256) s4[i] = w4[i];
    }
    int wid = tid >> 6, lane = tid & 63;
    int node = blockIdx.x * 4 + wid;
    if (node >= N) node = N - 1;  // duplicate work on ragged tail; same value written
    float h = hcat[(size_t)node * 256 + hoff + lane];
    sh[wid][lane] = h;
    __syncthreads();
    // r = sum(h * ar) via butterfly
    float p = h * ar[lane];
#pragma unroll
    for (int m = 1; m < 64; m <<= 1) p += __shfl_xor(p, m, 64);
    float acc = 0.f;
#pragma unroll 8
    for (int k = 0; k < 64; k++) acc += sh[wid][k] * sW[k * 64 + lane];
    g[(size_t)node * 64 + lane] = acc;
    if (lane == 0) r[node] = p;
}

// ---------------- per-layer gate conv: one wave per dst node ----------------
__global__ __launch_bounds__(256) void k_conv(const int* off, const int* src_perm,
                                              const float* attr_perm, const float* g,
                                              const float* r, const float* w1,
                                              const float* al, const float* w2,
                                              const float* bias, float* hcat,
                                              int outcol, int N) {
    __shared__ float sW2[64 * 64];
    __shared__ float sS[4][64];
    int tid = threadIdx.x;
    {
        const float4* w4 = (const float4*)w2;
        float4* s4 = (float4*)sW2;
        for (int i = tid; i < 1024; i += 256) s4[i] = w4[i];
    }
    int wid = tid >> 6, lane = tid & 63;
    int node = blockIdx.x * 4 + wid;
    if (node >= N) node = N - 1;

    float w1b[7];
#pragma unroll
    for (int k = 0; k < 7; k++) w1b[k] = w1[(64 + k) * 64 + lane];
    float alj = al[lane];
    float ri = r[node];
    int e0 = off[node], e1 = off[node + 1];

    float m = -INFINITY, den = 0.f, s = 0.f;
    for (int e = e0; e < e1; e++) {
        int sn = src_perm[e];
        float gj = g[(size_t)sn * 64 + lane];
        const float4* ap = (const float4*)(attr_perm + (size_t)e * 8);
        float4 a0 = ap[0], a1 = ap[1];
        float c = a0.x * w1b[0] + a0.y * w1b[1] + a0.z * w1b[2] + a0.w * w1b[3] +
                  a1.x * w1b[4] + a1.y * w1b[5] + a1.z * w1b[6];
        float x = lrelu(gj + c);
        float p = x * alj;
#pragma unroll
        for (int mk = 1; mk < 64; mk <<= 1) p += __shfl_xor(p, mk, 64);
        float alpha = lrelu(p + ri);
        float mn = fmaxf(m, alpha);
        float sc = __expf(m - mn);     // m = -inf on first iter -> 0
        float w = __expf(alpha - mn);
        s = s * sc + w * x;
        den = den * sc + w;
        m = mn;
    }
    float agg = s / (den + 1e-16f);
    sS[wid][lane] = agg;
    __syncthreads();  // covers sW2 load too (first read of sW2 is below)
    float acc = bias[lane];
#pragma unroll 8
    for (int k = 0; k < 64; k++) acc += sS[wid][k] * sW2[k * 64 + lane];
    hcat[(size_t)node * 256 + outcol + lane] = fmaxf(acc, 0.f);
}

// ---------------- head: fc1 + relu + fc2 + sigmoid ----------------
__global__ void k_head(const float* hcat, const float* f1w, const float* f1b,
                       const float* f2w, const float* f2b, float* out, int N) {
    int i = blockIdx.x * blockDim.x + threadIdx.x;
    if (i >= N) return;
    float z[20];
#pragma unroll
    for (int j = 0; j < 20; j++) z[j] = f1b[j];
    const float* hr = hcat + (size_t)i * 256;
    for (int k = 0; k < 256; k++) {
        float h = hr[k];
#pragma unroll
        for (int j = 0; j < 20; j++) z[j] += h * f1w[k * 20 + j];
    }
    float o = f2b[0];
#pragma unroll
    for (int j = 0; j < 20; j++) o += fmaxf(z[j], 0.f) * f2w[j];
    out[i] = 1.f / (1.f + __expf(-o));
}

extern "C" void kernel_launch(void* const* d_in, const int* in_sizes, int n_in,
                              void* d_out, int out_size, void* d_ws, size_t ws_size,
                              hipStream_t stream) {
    const int*   x     = (const int*)d_in[0];
    const int*   eidx  = (const int*)d_in[1];
    const float* eattr = (const float*)d_in[2];
    const float* emb   = (const float*)d_in[3];
    const float* lin1  = (const float*)d_in[4];   // [3,71,64]
    const float* attl  = (const float*)d_in[5];   // [3,64]
    const float* attr_ = (const float*)d_in[6];   // [3,64]
    const float* lin2  = (const float*)d_in[7];   // [3,64,64]
    const float* gbias = (const float*)d_in[8];   // [3,64]
    const float* f1w   = (const float*)d_in[9];   // [256,20]
    const float* f1b   = (const float*)d_in[10];
    const float* f2w   = (const float*)d_in[11];
    const float* f2b   = (const float*)d_in[12];
    float* out = (float*)d_out;

    int N = in_sizes[0];
    int E = in_sizes[1] / 2;
    const int* src = eidx;
    const int* dst = eidx + E;

    // workspace carve (256B aligned)
    char* p = (char*)d_ws;
    auto alloc = [&](size_t bytes) { void* q = (void*)p; p += (bytes + 255) & ~(size_t)255; return q; };
    float* hcat      = (float*)alloc((size_t)N * 256 * 4);
    float* g         = (float*)alloc((size_t)N * 64 * 4);
    float* r         = (float*)alloc((size_t)N * 4);
    int*   off       = (int*)alloc((size_t)(N + 1) * 4);
    int*   deg       = (int*)alloc((size_t)N * 4);
    int*   cur       = (int*)alloc((size_t)N * 4);
    int*   src_perm  = (int*)alloc((size_t)E * 4);
    float* attr_perm = (float*)alloc((size_t)E * 8 * 4);

    k_zero<<<(N + 255) / 256, 256, 0, stream>>>(deg, cur, N);
    k_count<<<(E + 255) / 256, 256, 0, stream>>>(dst, deg, E);
    k_scan<<<1, 1024, 0, stream>>>(deg, off, N);
    k_fill<<<(E + 255) / 256, 256, 0, stream>>>(src, dst, eattr, off, cur, src_perm, attr_perm, E);
    k_embed<<<((size_t)N * 64 + 255) / 256, 256, 0, stream>>>(x, emb, hcat, N);

    int nb = (N + 3) / 4;
    for (int l = 0; l < 3; l++) {
        k_prep<<<nb, 256, 0, stream>>>(hcat, 64 * l, lin1 + (size_t)l * 71 * 64,
                                       attr_ + l * 64, g, r, N);
        k_conv<<<nb, 256, 0, stream>>>(off, src_perm, attr_perm, g, r,
                                       lin1 + (size_t)l * 71 * 64, attl + l * 64,
                                       lin2 + (size_t)l * 4096, gbias + l * 64,
                                       hcat, 64 * (l + 1), N);
    }
    k_head<<<(N + 255) / 256, 256, 0, stream>>>(hcat, f1w, f1b, f2w, f2b, out, N);
}

// Round 2
// 713.932 us; speedup vs baseline: 1.5453x; 1.5453x over previous
//
#include <hip/hip_runtime.h>
#include <hip/hip_bf16.h>
#include <math.h>

#define NEG 0.01f

__device__ __forceinline__ float lrelu(float x) { return x > 0.f ? x : NEG * x; }

// sum across each 16-lane row via DPP; result in all 16 lanes of the row
__device__ __forceinline__ float q16_allsum(float v) {
    int x;
    x = __builtin_amdgcn_update_dpp(0, __float_as_int(v), 0xB1, 0xF, 0xF, true);  v += __int_as_float(x); // quad_perm [1,0,3,2] : xor1
    x = __builtin_amdgcn_update_dpp(0, __float_as_int(v), 0x4E, 0xF, 0xF, true);  v += __int_as_float(x); // quad_perm [2,3,0,1] : xor2
    x = __builtin_amdgcn_update_dpp(0, __float_as_int(v), 0x124, 0xF, 0xF, true); v += __int_as_float(x); // row_ror:4
    x = __builtin_amdgcn_update_dpp(0, __float_as_int(v), 0x128, 0xF, 0xF, true); v += __int_as_float(x); // row_ror:8
    return v;
}

// sum the four 16-lane quarters together (xor16 via ds_swizzle, xor32 via shfl)
__device__ __forceinline__ float x16_32_sum(float v) {
    v += __int_as_float(__builtin_amdgcn_ds_swizzle(__float_as_int(v), 0x401F)); // xor 16
    v += __shfl_xor(v, 32, 64);
    return v;
}

// ---------------- CSR build ----------------
__global__ void k_zero(int* deg, int* cur, int n) {
    int i = blockIdx.x * blockDim.x + threadIdx.x;
    if (i < n) { deg[i] = 0; cur[i] = 0; }
}

__global__ void k_count(const int* dst, int* deg, int E) {
    int e = blockIdx.x * blockDim.x + threadIdx.x;
    if (e < E) atomicAdd(&deg[dst[e]], 1);
}

__global__ __launch_bounds__(1024) void k_scan(const int* deg, int* off, int n) {
    __shared__ int part[1024];
    int t = threadIdx.x;
    int chunk = (n + 1023) / 1024;
    int lo = t * chunk, hi = min(n, lo + chunk);
    int s = 0;
    for (int i = lo; i < hi; i++) s += deg[i];
    part[t] = s;
    __syncthreads();
    for (int d = 1; d < 1024; d <<= 1) {
        int v = (t >= d) ? part[t - d] : 0;
        __syncthreads();
        part[t] += v;
        __syncthreads();
    }
    int run = (t == 0) ? 0 : part[t - 1];
    for (int i = lo; i < hi; i++) { off[i] = run; run += deg[i]; }
    if (t == 0) off[n] = part[1023];
}

__global__ void k_fill(const int* src, const int* dst, const float* eattr,
                       const int* off, int* cur, int* src_perm, float* attr_perm, int E) {
    int e = blockIdx.x * blockDim.x + threadIdx.x;
    if (e >= E) return;
    int d = dst[e];
    int slot = off[d] + atomicAdd(&cur[d], 1);
    src_perm[slot] = src[e];
    float a[8];
#pragma unroll
    for (int k = 0; k < 7; k++) a[k] = eattr[e * 7 + k];
    a[7] = 0.f;
    float4* dst4 = (float4*)(attr_perm + (size_t)slot * 8);
    dst4[0] = make_float4(a[0], a[1], a[2], a[3]);
    dst4[1] = make_float4(a[4], a[5], a[6], a[7]);
}

// ---------------- embedding gather (float4) ----------------
__global__ void k_embed(const int* __restrict__ x, const float* __restrict__ emb,
                        float* __restrict__ hcat, int N) {
    int idx = blockIdx.x * blockDim.x + threadIdx.x;   // N*16 float4 units
    int node = idx >> 4, j4 = (idx & 15) * 4;
    if (node < N) {
        float4 v = *(const float4*)(emb + (size_t)x[node] * 64 + j4);
        *(float4*)(hcat + (size_t)node * 256 + j4) = v;
    }
}

// ---------------- tiled fp32 GEMM: C[N,64] = A[N,64] @ B[64,64] (+bias, relu) ----
// optional: r_out[n] = dot(A[n,:], ar) computed from the staged A tile
__global__ __launch_bounds__(256) void k_gemm64(
    const float* __restrict__ A, int a_stride,
    const float* __restrict__ B, const float* __restrict__ bias,
    float* __restrict__ C, int c_stride, int N, int do_relu,
    const float* __restrict__ ar, float* __restrict__ r_out)
{
    __shared__ __align__(16) float sA[64][132];   // [k][node], 132-pad keeps rows 16B-aligned
    __shared__ __align__(16) float sB[64 * 64];   // [k][col]
    __shared__ float sar[64];
    int tid = threadIdx.x;
    int row0 = blockIdx.x * 128;

    {   // stage B
        const float4* b4 = (const float4*)B;
        float4* s4 = (float4*)sB;
        for (int i = tid; i < 1024; i += 256) s4[i] = b4[i];
    }
    if (ar && tid < 64) sar[tid] = ar[tid];

    // stage A transposed: per pass, 16 nodes x 64 k; lanes: consecutive tid -> consecutive node
#pragma unroll
    for (int pass = 0; pass < 8; ++pass) {
        int nl = pass * 16 + (tid & 15);
        int k4 = (tid >> 4) * 4;
        int n = row0 + nl; if (n >= N) n = N - 1;
        float4 v = *(const float4*)(A + (size_t)n * a_stride + k4);
        sA[k4 + 0][nl] = v.x; sA[k4 + 1][nl] = v.y;
        sA[k4 + 2][nl] = v.z; sA[k4 + 3][nl] = v.w;
    }
    __syncthreads();

    int tr = tid >> 4, tc = tid & 15;
    int r0 = tr * 8, c0 = tc * 4;
    float acc[8][4];
#pragma unroll
    for (int i = 0; i < 8; i++)
#pragma unroll
        for (int j = 0; j < 4; j++) acc[i][j] = 0.f;

#pragma unroll 4
    for (int k = 0; k < 64; ++k) {
        float4 b4 = *(const float4*)(sB + k * 64 + c0);
        float4 a0 = *(const float4*)&sA[k][r0];
        float4 a1 = *(const float4*)&sA[k][r0 + 4];
#pragma unroll
        for (int j = 0; j < 4; j++) {
            float bj = (&b4.x)[j];
            acc[0][j] += a0.x * bj; acc[1][j] += a0.y * bj;
            acc[2][j] += a0.z * bj; acc[3][j] += a0.w * bj;
            acc[4][j] += a1.x * bj; acc[5][j] += a1.y * bj;
            acc[6][j] += a1.z * bj; acc[7][j] += a1.w * bj;
        }
    }

    float4 bv = make_float4(0.f, 0.f, 0.f, 0.f);
    if (bias) bv = *(const float4*)(bias + c0);
#pragma unroll
    for (int i = 0; i < 8; i++) {
        int n = row0 + r0 + i;
        if (n < N) {
            float4 o;
            o.x = acc[i][0] + bv.x; o.y = acc[i][1] + bv.y;
            o.z = acc[i][2] + bv.z; o.w = acc[i][3] + bv.w;
            if (do_relu) {
                o.x = fmaxf(o.x, 0.f); o.y = fmaxf(o.y, 0.f);
                o.z = fmaxf(o.z, 0.f); o.w = fmaxf(o.w, 0.f);
            }
            *(float4*)(C + (size_t)n * c_stride + c0) = o;
        }
    }

    if (r_out && tid < 128) {
        int n = row0 + tid;
        if (n < N) {
            float racc = 0.f;
#pragma unroll
            for (int k = 0; k < 64; k++) racc += sA[k][tid] * sar[k];
            r_out[n] = racc;
        }
    }
}

// ---------------- gate conv: one wave per node, 4 edges per iter (16 lanes each) ---
// writes agg = softmax-weighted sum of x_e into aggdst (row stride 256)
__global__ __launch_bounds__(256) void k_conv(
    const int* __restrict__ off, const int* __restrict__ src_perm,
    const float* __restrict__ attr_perm, const float* __restrict__ g,
    const float* __restrict__ r, const float* __restrict__ w1,
    const float* __restrict__ al, float* __restrict__ aggdst, int N)
{
    int lane = threadIdx.x & 63;
    int wid  = threadIdx.x >> 6;
    int node = blockIdx.x * 4 + wid;
    if (node >= N) return;                 // wave-uniform exit, no barriers in kernel
    int q = lane >> 4, l16 = lane & 15;

    float4 w1b[7];
#pragma unroll
    for (int k = 0; k < 7; k++)
        w1b[k] = *(const float4*)(w1 + (64 + k) * 64 + 4 * l16);
    float4 al4 = *(const float4*)(al + 4 * l16);
    float ri = r[node];
    int e0 = off[node], e1 = off[node + 1];

    float4 s = make_float4(0.f, 0.f, 0.f, 0.f);
    float den = 0.f;
    for (int e = e0; e < e1; e += 4) {
        int my_e = e + q;
        bool valid = my_e < e1;
        int ce = valid ? my_e : (e1 - 1);
        int sn = src_perm[ce];
        float4 gj = *(const float4*)(g + (size_t)sn * 64 + 4 * l16);
        const float4* ap = (const float4*)(attr_perm + (size_t)ce * 8);
        float4 a0 = ap[0], a1 = ap[1];
        float4 c;
        c.x = a0.x*w1b[0].x + a0.y*w1b[1].x + a0.z*w1b[2].x + a0.w*w1b[3].x
            + a1.x*w1b[4].x + a1.y*w1b[5].x + a1.z*w1b[6].x;
        c.y = a0.x*w1b[0].y + a0.y*w1b[1].y + a0.z*w1b[2].y + a0.w*w1b[3].y
            + a1.x*w1b[4].y + a1.y*w1b[5].y + a1.z*w1b[6].y;
        c.z = a0.x*w1b[0].z + a0.y*w1b[1].z + a0.z*w1b[2].z + a0.w*w1b[3].z
            + a1.x*w1b[4].z + a1.y*w1b[5].z + a1.z*w1b[6].z;
        c.w = a0.x*w1b[0].w + a0.y*w1b[1].w + a0.z*w1b[2].w + a0.w*w1b[3].w
            + a1.x*w1b[4].w + a1.y*w1b[5].w + a1.z*w1b[6].w;
        float4 xv;
        xv.x = lrelu(gj.x + c.x); xv.y = lrelu(gj.y + c.y);
        xv.z = lrelu(gj.z + c.z); xv.w = lrelu(gj.w + c.w);
        float p = xv.x*al4.x + xv.y*al4.y + xv.z*al4.z + xv.w*al4.w;
        p = q16_allsum(p);                       // full 64-dot of this quarter's edge
        float alpha = lrelu(p + ri);
        float w = valid ? __expf(alpha) : 0.f;   // no max-subtraction: |alpha| bounded
        s.x += w * xv.x; s.y += w * xv.y; s.z += w * xv.z; s.w += w * xv.w;
        den += w;
    }
    // combine the 4 quarters
    s.x = x16_32_sum(s.x); s.y = x16_32_sum(s.y);
    s.z = x16_32_sum(s.z); s.w = x16_32_sum(s.w);
    den = x16_32_sum(den);
    float inv = 1.f / (den + 1e-16f);
    if (q == 0) {
        float4 o = make_float4(s.x * inv, s.y * inv, s.z * inv, s.w * inv);
        *(float4*)(aggdst + (size_t)node * 256 + 4 * l16) = o;
    }
}

// ---------------- head: fc1 + relu + fc2 + sigmoid ----------------
__global__ void k_head(const float* __restrict__ hcat, const float* __restrict__ f1w,
                       const float* __restrict__ f1b, const float* __restrict__ f2w,
                       const float* __restrict__ f2b, float* __restrict__ out, int N) {
    int i = blockIdx.x * blockDim.x + threadIdx.x;
    if (i >= N) return;
    float z[20];
#pragma unroll
    for (int j = 0; j < 20; j++) z[j] = f1b[j];
    const float4* hr = (const float4*)(hcat + (size_t)i * 256);
    for (int k4 = 0; k4 < 64; k4++) {
        float4 h = hr[k4];
        const float* wr = f1w + k4 * 4 * 20;
#pragma unroll
        for (int j = 0; j < 20; j++)
            z[j] += h.x * wr[j] + h.y * wr[20 + j] + h.z * wr[40 + j] + h.w * wr[60 + j];
    }
    float o = f2b[0];
#pragma unroll
    for (int j = 0; j < 20; j++) o += fmaxf(z[j], 0.f) * f2w[j];
    out[i] = 1.f / (1.f + __expf(-o));
}

extern "C" void kernel_launch(void* const* d_in, const int* in_sizes, int n_in,
                              void* d_out, int out_size, void* d_ws, size_t ws_size,
                              hipStream_t stream) {
    const int*   x     = (const int*)d_in[0];
    const int*   eidx  = (const int*)d_in[1];
    const float* eattr = (const float*)d_in[2];
    const float* emb   = (const float*)d_in[3];
    const float* lin1  = (const float*)d_in[4];   // [3,71,64]
    const float* attl  = (const float*)d_in[5];   // [3,64]
    const float* attr_ = (const float*)d_in[6];   // [3,64]
    const float* lin2  = (const float*)d_in[7];   // [3,64,64]
    const float* gbias = (const float*)d_in[8];   // [3,64]
    const float* f1w   = (const float*)d_in[9];   // [256,20]
    const float* f1b   = (const float*)d_in[10];
    const float* f2w   = (const float*)d_in[11];
    const float* f2b   = (const float*)d_in[12];
    float* out = (float*)d_out;

    int N = in_sizes[0];
    int E = in_sizes[1] / 2;
    const int* src = eidx;
    const int* dst = eidx + E;

    // workspace carve (256B aligned) — total ~110 MB (same as proven round-1 layout)
    char* p = (char*)d_ws;
    auto alloc = [&](size_t bytes) { void* q = (void*)p; p += (bytes + 255) & ~(size_t)255; return q; };
    float* hcat      = (float*)alloc((size_t)N * 256 * 4);
    float* g         = (float*)alloc((size_t)N * 64 * 4);
    float* r         = (float*)alloc((size_t)N * 4);
    int*   off       = (int*)alloc((size_t)(N + 1) * 4);
    int*   deg       = (int*)alloc((size_t)N * 4);
    int*   cur       = (int*)alloc((size_t)N * 4);
    int*   src_perm  = (int*)alloc((size_t)E * 4);
    float* attr_perm = (float*)alloc((size_t)E * 8 * 4);

    k_zero<<<(N + 255) / 256, 256, 0, stream>>>(deg, cur, N);
    k_count<<<(E + 255) / 256, 256, 0, stream>>>(dst, deg, E);
    k_scan<<<1, 1024, 0, stream>>>(deg, off, N);
    k_fill<<<(E + 255) / 256, 256, 0, stream>>>(src, dst, eattr, off, cur, src_perm, attr_perm, E);
    k_embed<<<(N * 16 + 255) / 256, 256, 0, stream>>>(x, emb, hcat, N);

    int nbg = (N + 127) / 128;
    int nbc = (N + 3) / 4;
    for (int l = 0; l < 3; l++) {
        const float* w1l = lin1 + (size_t)l * 71 * 64;
        // g = h_l @ W1a  (+ r = h_l . att_r fused)
        k_gemm64<<<nbg, 256, 0, stream>>>(hcat + 64 * l, 256, w1l, nullptr,
                                          g, 64, N, 0, attr_ + l * 64, r);
        // agg -> hcat column block l+1
        k_conv<<<nbc, 256, 0, stream>>>(off, src_perm, attr_perm, g, r,
                                        w1l, attl + l * 64, hcat + 64 * (l + 1), N);
        // in-place: hcat[:, l+1 block] = relu(agg @ W2 + b)
        k_gemm64<<<nbg, 256, 0, stream>>>(hcat + 64 * (l + 1), 256,
                                          lin2 + (size_t)l * 4096, gbias + l * 64,
                                          hcat + 64 * (l + 1), 256, N, 1,
                                          nullptr, nullptr);
    }
    k_head<<<(N + 255) / 256, 256, 0, stream>>>(hcat, f1w, f1b, f2w, f2b, out, N);
}

// Round 3
// 692.937 us; speedup vs baseline: 1.5921x; 1.0303x over previous
//
#include <hip/hip_runtime.h>
#include <hip/hip_bf16.h>
#include <math.h>

#define NEG 0.01f

__device__ __forceinline__ float lrelu(float x) { return x > 0.f ? x : NEG * x; }

// sum across each 16-lane row via DPP; result in all 16 lanes of the row
__device__ __forceinline__ float q16_allsum(float v) {
    int x;
    x = __builtin_amdgcn_update_dpp(0, __float_as_int(v), 0xB1, 0xF, 0xF, true);  v += __int_as_float(x); // quad_perm xor1
    x = __builtin_amdgcn_update_dpp(0, __float_as_int(v), 0x4E, 0xF, 0xF, true);  v += __int_as_float(x); // quad_perm xor2
    x = __builtin_amdgcn_update_dpp(0, __float_as_int(v), 0x124, 0xF, 0xF, true); v += __int_as_float(x); // row_ror:4
    x = __builtin_amdgcn_update_dpp(0, __float_as_int(v), 0x128, 0xF, 0xF, true); v += __int_as_float(x); // row_ror:8
    return v;
}

// sum the four 16-lane quarters together (xor16 via ds_swizzle, xor32 via shfl)
__device__ __forceinline__ float x16_32_sum(float v) {
    v += __int_as_float(__builtin_amdgcn_ds_swizzle(__float_as_int(v), 0x401F)); // xor 16
    v += __shfl_xor(v, 32, 64);
    return v;
}

// ---------------- CSR build ----------------
__global__ void k_zero(int* deg, int n) {
    int i = blockIdx.x * blockDim.x + threadIdx.x;
    if (i < n) deg[i] = 0;
}

__global__ void k_count(const int* dst, int* deg, int E) {
    int e = blockIdx.x * blockDim.x + threadIdx.x;
    if (e < E) atomicAdd(&deg[dst[e]], 1);
}

__global__ __launch_bounds__(1024) void k_scan(const int* deg, int* off, int n) {
    __shared__ int part[1024];
    int t = threadIdx.x;
    int chunk = (n + 1023) / 1024;
    int lo = t * chunk, hi = min(n, lo + chunk);
    int s = 0;
    for (int i = lo; i < hi; i++) s += deg[i];
    part[t] = s;
    __syncthreads();
    for (int d = 1; d < 1024; d <<= 1) {
        int v = (t >= d) ? part[t - d] : 0;
        __syncthreads();
        part[t] += v;
        __syncthreads();
    }
    int run = (t == 0) ? 0 : part[t - 1];
    for (int i = lo; i < hi; i++) { off[i] = run; run += deg[i]; }
    if (t == 0) off[n] = part[1023];
}

// one 32 B record per edge: {a0,a1,a2,a3 | a4,a5,a6, src_bits}
// single scattered line per edge (was 2: attr + src_perm); deg doubles as countdown
__global__ void k_fill(const int* __restrict__ src, const int* __restrict__ dst,
                       const float* __restrict__ eattr, const int* __restrict__ off,
                       int* __restrict__ deg, float* __restrict__ rec, int E) {
    int e = blockIdx.x * blockDim.x + threadIdx.x;
    if (e >= E) return;
    int d = dst[e];
    int slot = off[d] + atomicSub(&deg[d], 1) - 1;
    float a[7];
#pragma unroll
    for (int k = 0; k < 7; k++) a[k] = eattr[e * 7 + k];
    float4* rp = (float4*)(rec + (size_t)slot * 8);
    rp[0] = make_float4(a[0], a[1], a[2], a[3]);
    rp[1] = make_float4(a[4], a[5], a[6], __int_as_float(src[e]));
}

// ---------------- embedding gather (float4) ----------------
__global__ void k_embed(const int* __restrict__ x, const float* __restrict__ emb,
                        float* __restrict__ hcat, int N) {
    int idx = blockIdx.x * blockDim.x + threadIdx.x;   // N*16 float4 units
    int node = idx >> 4, j4 = (idx & 15) * 4;
    if (node < N) {
        float4 v = *(const float4*)(emb + (size_t)x[node] * 64 + j4);
        *(float4*)(hcat + (size_t)node * 256 + j4) = v;
    }
}

// ---------------- tiled fp32 GEMM: C[N,64] = A[N,64] @ B[64,64] (+bias, relu) ----
// optional: r_out[n] = dot(A[n,:], ar) computed from the staged A tile
__global__ __launch_bounds__(256) void k_gemm64(
    const float* __restrict__ A, int a_stride,
    const float* __restrict__ B, const float* __restrict__ bias,
    float* __restrict__ C, int c_stride, int N, int do_relu,
    const float* __restrict__ ar, float* __restrict__ r_out)
{
    __shared__ __align__(16) float sA[64][132];   // [k][node], 132-pad keeps rows 16B-aligned
    __shared__ __align__(16) float sB[64 * 64];   // [k][col]
    __shared__ float sar[64];
    int tid = threadIdx.x;
    int row0 = blockIdx.x * 128;

    {   // stage B
        const float4* b4 = (const float4*)B;
        float4* s4 = (float4*)sB;
        for (int i = tid; i < 1024; i += 256) s4[i] = b4[i];
    }
    if (ar && tid < 64) sar[tid] = ar[tid];

#pragma unroll
    for (int pass = 0; pass < 8; ++pass) {
        int nl = pass * 16 + (tid & 15);
        int k4 = (tid >> 4) * 4;
        int n = row0 + nl; if (n >= N) n = N - 1;
        float4 v = *(const float4*)(A + (size_t)n * a_stride + k4);
        sA[k4 + 0][nl] = v.x; sA[k4 + 1][nl] = v.y;
        sA[k4 + 2][nl] = v.z; sA[k4 + 3][nl] = v.w;
    }
    __syncthreads();

    int tr = tid >> 4, tc = tid & 15;
    int r0 = tr * 8, c0 = tc * 4;
    float acc[8][4];
#pragma unroll
    for (int i = 0; i < 8; i++)
#pragma unroll
        for (int j = 0; j < 4; j++) acc[i][j] = 0.f;

#pragma unroll 4
    for (int k = 0; k < 64; ++k) {
        float4 b4 = *(const float4*)(sB + k * 64 + c0);
        float4 a0 = *(const float4*)&sA[k][r0];
        float4 a1 = *(const float4*)&sA[k][r0 + 4];
#pragma unroll
        for (int j = 0; j < 4; j++) {
            float bj = (&b4.x)[j];
            acc[0][j] += a0.x * bj; acc[1][j] += a0.y * bj;
            acc[2][j] += a0.z * bj; acc[3][j] += a0.w * bj;
            acc[4][j] += a1.x * bj; acc[5][j] += a1.y * bj;
            acc[6][j] += a1.z * bj; acc[7][j] += a1.w * bj;
        }
    }

    float4 bv = make_float4(0.f, 0.f, 0.f, 0.f);
    if (bias) bv = *(const float4*)(bias + c0);
#pragma unroll
    for (int i = 0; i < 8; i++) {
        int n = row0 + r0 + i;
        if (n < N) {
            float4 o;
            o.x = acc[i][0] + bv.x; o.y = acc[i][1] + bv.y;
            o.z = acc[i][2] + bv.z; o.w = acc[i][3] + bv.w;
            if (do_relu) {
                o.x = fmaxf(o.x, 0.f); o.y = fmaxf(o.y, 0.f);
                o.z = fmaxf(o.z, 0.f); o.w = fmaxf(o.w, 0.f);
            }
            *(float4*)(C + (size_t)n * c_stride + c0) = o;
        }
    }

    if (r_out && tid < 128) {
        int n = row0 + tid;
        if (n < N) {
            float racc = 0.f;
#pragma unroll
            for (int k = 0; k < 64; k++) racc += sA[k][tid] * sar[k];
            r_out[n] = racc;
        }
    }
}

// ---------------- gate conv: one wave per node, 8 edges per iter (2 per quarter) ---
__global__ __launch_bounds__(256) void k_conv(
    const int* __restrict__ off, const float* __restrict__ rec,
    const float* __restrict__ g, const float* __restrict__ r,
    const float* __restrict__ w1, const float* __restrict__ al,
    float* __restrict__ aggdst, int N)
{
    int lane = threadIdx.x & 63;
    int wid  = threadIdx.x >> 6;
    int node = blockIdx.x * 4 + wid;
    if (node >= N) return;                 // wave-uniform exit, no barriers in kernel
    int q = lane >> 4, l16 = lane & 15;

    float4 w1b[7];
#pragma unroll
    for (int k = 0; k < 7; k++)
        w1b[k] = *(const float4*)(w1 + (64 + k) * 64 + 4 * l16);
    float4 al4 = *(const float4*)(al + 4 * l16);
    float ri = r[node];
    int e0 = off[node], e1 = off[node + 1];

    float4 s = make_float4(0.f, 0.f, 0.f, 0.f);
    float den = 0.f;
    for (int e = e0; e < e1; e += 8) {
        int ea = e + q, eb = e + 4 + q;
        bool va = ea < e1, vb = eb < e1;
        int ca = va ? ea : e0;             // e0 always valid inside loop
        int cb = vb ? eb : e0;
        // 4 independent loads issue before any dependent compute
        const float4* rpa = (const float4*)(rec + (size_t)ca * 8);
        const float4* rpb = (const float4*)(rec + (size_t)cb * 8);
        float4 a0 = rpa[0], a1 = rpa[1];
        float4 b0 = rpb[0], b1 = rpb[1];
        int sna = __float_as_int(a1.w), snb = __float_as_int(b1.w);
        float4 ga = *(const float4*)(g + (size_t)sna * 64 + 4 * l16);
        float4 gb = *(const float4*)(g + (size_t)snb * 64 + 4 * l16);

        float4 cA;
        cA.x = a0.x*w1b[0].x + a0.y*w1b[1].x + a0.z*w1b[2].x + a0.w*w1b[3].x
             + a1.x*w1b[4].x + a1.y*w1b[5].x + a1.z*w1b[6].x;
        cA.y = a0.x*w1b[0].y + a0.y*w1b[1].y + a0.z*w1b[2].y + a0.w*w1b[3].y
             + a1.x*w1b[4].y + a1.y*w1b[5].y + a1.z*w1b[6].y;
        cA.z = a0.x*w1b[0].z + a0.y*w1b[1].z + a0.z*w1b[2].z + a0.w*w1b[3].z
             + a1.x*w1b[4].z + a1.y*w1b[5].z + a1.z*w1b[6].z;
        cA.w = a0.x*w1b[0].w + a0.y*w1b[1].w + a0.z*w1b[2].w + a0.w*w1b[3].w
             + a1.x*w1b[4].w + a1.y*w1b[5].w + a1.z*w1b[6].w;
        float4 xa;
        xa.x = lrelu(ga.x + cA.x); xa.y = lrelu(ga.y + cA.y);
        xa.z = lrelu(ga.z + cA.z); xa.w = lrelu(ga.w + cA.w);
        float pa = xa.x*al4.x + xa.y*al4.y + xa.z*al4.z + xa.w*al4.w;

        float4 cB;
        cB.x = b0.x*w1b[0].x + b0.y*w1b[1].x + b0.z*w1b[2].x + b0.w*w1b[3].x
             + b1.x*w1b[4].x + b1.y*w1b[5].x + b1.z*w1b[6].x;
        cB.y = b0.x*w1b[0].y + b0.y*w1b[1].y + b0.z*w1b[2].y + b0.w*w1b[3].y
             + b1.x*w1b[4].y + b1.y*w1b[5].y + b1.z*w1b[6].y;
        cB.z = b0.x*w1b[0].z + b0.y*w1b[1].z + b0.z*w1b[2].z + b0.w*w1b[3].z
             + b1.x*w1b[4].z + b1.y*w1b[5].z + b1.z*w1b[6].z;
        cB.w = b0.x*w1b[0].w + b0.y*w1b[1].w + b0.z*w1b[2].w + b0.w*w1b[3].w
             + b1.x*w1b[4].w + b1.y*w1b[5].w + b1.z*w1b[6].w;
        float4 xb;
        xb.x = lrelu(gb.x + cB.x); xb.y = lrelu(gb.y + cB.y);
        xb.z = lrelu(gb.z + cB.z); xb.w = lrelu(gb.w + cB.w);
        float pb = xb.x*al4.x + xb.y*al4.y + xb.z*al4.z + xb.w*al4.w;

        pa = q16_allsum(pa);
        pb = q16_allsum(pb);
        float wa = va ? __expf(lrelu(pa + ri)) : 0.f;  // |alpha| bounded, no max-sub
        float wb = vb ? __expf(lrelu(pb + ri)) : 0.f;
        s.x += wa * xa.x + wb * xb.x;
        s.y += wa * xa.y + wb * xb.y;
        s.z += wa * xa.z + wb * xb.z;
        s.w += wa * xa.w + wb * xb.w;
        den += wa + wb;
    }
    // combine the 4 quarters
    s.x = x16_32_sum(s.x); s.y = x16_32_sum(s.y);
    s.z = x16_32_sum(s.z); s.w = x16_32_sum(s.w);
    den = x16_32_sum(den);
    float inv = 1.f / (den + 1e-16f);
    if (q == 0) {
        float4 o = make_float4(s.x * inv, s.y * inv, s.z * inv, s.w * inv);
        *(float4*)(aggdst + (size_t)node * 256 + 4 * l16) = o;
    }
}

// ---------------- head: fc1 + relu + fc2 + sigmoid ----------------
__global__ void k_head(const float* __restrict__ hcat, const float* __restrict__ f1w,
                       const float* __restrict__ f1b, const float* __restrict__ f2w,
                       const float* __restrict__ f2b, float* __restrict__ out, int N) {
    int i = blockIdx.x * blockDim.x + threadIdx.x;
    if (i >= N) return;
    float z[20];
#pragma unroll
    for (int j = 0; j < 20; j++) z[j] = f1b[j];
    const float4* hr = (const float4*)(hcat + (size_t)i * 256);
    for (int k4 = 0; k4 < 64; k4++) {
        float4 h = hr[k4];
        const float* wr = f1w + k4 * 4 * 20;
#pragma unroll
        for (int j = 0; j < 20; j++)
            z[j] += h.x * wr[j] + h.y * wr[20 + j] + h.z * wr[40 + j] + h.w * wr[60 + j];
    }
    float o = f2b[0];
#pragma unroll
    for (int j = 0; j < 20; j++) o += fmaxf(z[j], 0.f) * f2w[j];
    out[i] = 1.f / (1.f + __expf(-o));
}

extern "C" void kernel_launch(void* const* d_in, const int* in_sizes, int n_in,
                              void* d_out, int out_size, void* d_ws, size_t ws_size,
                              hipStream_t stream) {
    const int*   x     = (const int*)d_in[0];
    const int*   eidx  = (const int*)d_in[1];
    const float* eattr = (const float*)d_in[2];
    const float* emb   = (const float*)d_in[3];
    const float* lin1  = (const float*)d_in[4];   // [3,71,64]
    const float* attl  = (const float*)d_in[5];   // [3,64]
    const float* attr_ = (const float*)d_in[6];   // [3,64]
    const float* lin2  = (const float*)d_in[7];   // [3,64,64]
    const float* gbias = (const float*)d_in[8];   // [3,64]
    const float* f1w   = (const float*)d_in[9];   // [256,20]
    const float* f1b   = (const float*)d_in[10];
    const float* f2w   = (const float*)d_in[11];
    const float* f2b   = (const float*)d_in[12];
    float* out = (float*)d_out;

    int N = in_sizes[0];
    int E = in_sizes[1] / 2;
    const int* src = eidx;
    const int* dst = eidx + E;

    // workspace carve (256B aligned) — ~105 MB
    char* p = (char*)d_ws;
    auto alloc = [&](size_t bytes) { void* q = (void*)p; p += (bytes + 255) & ~(size_t)255; return q; };
    float* hcat = (float*)alloc((size_t)N * 256 * 4);
    float* g    = (float*)alloc((size_t)N * 64 * 4);
    float* r    = (float*)alloc((size_t)N * 4);
    int*   off  = (int*)alloc((size_t)(N + 1) * 4);
    int*   deg  = (int*)alloc((size_t)N * 4);
    float* rec  = (float*)alloc((size_t)E * 8 * 4);   // 32 B/edge: attr + src

    k_zero<<<(N + 255) / 256, 256, 0, stream>>>(deg, N);
    k_count<<<(E + 255) / 256, 256, 0, stream>>>(dst, deg, E);
    k_scan<<<1, 1024, 0, stream>>>(deg, off, N);
    k_fill<<<(E + 255) / 256, 256, 0, stream>>>(src, dst, eattr, off, deg, rec, E);
    k_embed<<<(N * 16 + 255) / 256, 256, 0, stream>>>(x, emb, hcat, N);

    int nbg = (N + 127) / 128;
    int nbc = (N + 3) / 4;
    for (int l = 0; l < 3; l++) {
        const float* w1l = lin1 + (size_t)l * 71 * 64;
        k_gemm64<<<nbg, 256, 0, stream>>>(hcat + 64 * l, 256, w1l, nullptr,
                                          g, 64, N, 0, attr_ + l * 64, r);
        k_conv<<<nbc, 256, 0, stream>>>(off, rec, g, r, w1l, attl + l * 64,
                                        hcat + 64 * (l + 1), N);
        k_gemm64<<<nbg, 256, 0, stream>>>(hcat + 64 * (l + 1), 256,
                                          lin2 + (size_t)l * 4096, gbias + l * 64,
                                          hcat + 64 * (l + 1), 256, N, 1,
                                          nullptr, nullptr);
    }
    k_head<<<(N + 255) / 256, 256, 0, stream>>>(hcat, f1w, f1b, f2w, f2b, out, N);
}

// Round 4
// 632.056 us; speedup vs baseline: 1.7455x; 1.0963x over previous
//
#include <hip/hip_runtime.h>
#include <hip/hip_bf16.h>
#include <hip/hip_fp16.h>
#include <math.h>

#define NEG 0.01f

__device__ __forceinline__ float lrelu(float x) { return x > 0.f ? x : NEG * x; }

// sum across each 16-lane row via DPP; result in all 16 lanes of the row
__device__ __forceinline__ float q16_allsum(float v) {
    int x;
    x = __builtin_amdgcn_update_dpp(0, __float_as_int(v), 0xB1, 0xF, 0xF, true);  v += __int_as_float(x); // quad_perm xor1
    x = __builtin_amdgcn_update_dpp(0, __float_as_int(v), 0x4E, 0xF, 0xF, true);  v += __int_as_float(x); // quad_perm xor2
    x = __builtin_amdgcn_update_dpp(0, __float_as_int(v), 0x124, 0xF, 0xF, true); v += __int_as_float(x); // row_ror:4
    x = __builtin_amdgcn_update_dpp(0, __float_as_int(v), 0x128, 0xF, 0xF, true); v += __int_as_float(x); // row_ror:8
    return v;
}

__device__ __forceinline__ float x16_32_sum(float v) {
    v += __int_as_float(__builtin_amdgcn_ds_swizzle(__float_as_int(v), 0x401F)); // xor 16
    v += __shfl_xor(v, 32, 64);
    return v;
}

// load 4 consecutive halfs (8 B aligned) as float4
__device__ __forceinline__ float4 load_h4(const __half* p) {
    const __half2* q = (const __half2*)p;
    __half2 a = q[0], b = q[1];
    float2 fa = __half22float2(a), fb = __half22float2(b);
    return make_float4(fa.x, fa.y, fb.x, fb.y);
}

// ---------------- CSR build ----------------
__global__ void k_zero(int* deg, int n) {
    int i = blockIdx.x * blockDim.x + threadIdx.x;
    if (i < n) deg[i] = 0;
}

// count + record each edge's rank within its dst segment (coalesced store)
__global__ void k_count(const int* __restrict__ dst, int* __restrict__ deg,
                        int* __restrict__ rank, int E) {
    int e = blockIdx.x * blockDim.x + threadIdx.x;
    if (e < E) rank[e] = atomicAdd(&deg[dst[e]], 1);
}

// ---- parallel exclusive scan of deg -> off (3 kernels; nb <= 256 assumed) ----
__global__ __launch_bounds__(256) void k_scan_part(const int* __restrict__ deg,
                                                   int* __restrict__ bsum, int n) {
    __shared__ int sh[256];
    int b = blockIdx.x, t = threadIdx.x;
    int i0 = b * 1024 + t * 4;
    int s = 0;
    if (i0 + 3 < n) { int4 v = *(const int4*)(deg + i0); s = v.x + v.y + v.z + v.w; }
    else { for (int k = 0; k < 4; k++) if (i0 + k < n) s += deg[i0 + k]; }
    sh[t] = s; __syncthreads();
    for (int d = 128; d > 0; d >>= 1) { if (t < d) sh[t] += sh[t + d]; __syncthreads(); }
    if (t == 0) bsum[b] = sh[0];
}

__global__ __launch_bounds__(256) void k_scan_mid(const int* __restrict__ bsum,
                                                  int* __restrict__ bbase,
                                                  int* __restrict__ off, int nb, int n) {
    __shared__ int sh[256];
    int t = threadIdx.x;
    int v = (t < nb) ? bsum[t] : 0;
    sh[t] = v; __syncthreads();
    for (int d = 1; d < 256; d <<= 1) {
        int u = (t >= d) ? sh[t - d] : 0;
        __syncthreads(); sh[t] += u; __syncthreads();
    }
    if (t < nb) bbase[t] = sh[t] - v;          // exclusive block prefix
    if (t == nb - 1) off[n] = sh[t];           // total = E
}

__global__ __launch_bounds__(256) void k_scan_out(const int* __restrict__ deg,
                                                  const int* __restrict__ bbase,
                                                  int* __restrict__ off, int n) {
    __shared__ int sh[256];
    int b = blockIdx.x, t = threadIdx.x;
    int i0 = b * 1024 + t * 4;
    int4 v = make_int4(0, 0, 0, 0);
    if (i0 + 3 < n) v = *(const int4*)(deg + i0);
    else {
        v.x = (i0     < n) ? deg[i0]     : 0;
        v.y = (i0 + 1 < n) ? deg[i0 + 1] : 0;
        v.z = (i0 + 2 < n) ? deg[i0 + 2] : 0;
        v.w = (i0 + 3 < n) ? deg[i0 + 3] : 0;
    }
    int s = v.x + v.y + v.z + v.w;
    sh[t] = s; __syncthreads();
    for (int d = 1; d < 256; d <<= 1) {
        int u = (t >= d) ? sh[t - d] : 0;
        __syncthreads(); sh[t] += u; __syncthreads();
    }
    int base = bbase[b] + sh[t] - s;           // exclusive within block
    if (i0     < n) off[i0]     = base;
    if (i0 + 1 < n) off[i0 + 1] = base + v.x;
    if (i0 + 2 < n) off[i0 + 2] = base + v.x + v.y;
    if (i0 + 3 < n) off[i0 + 3] = base + v.x + v.y + v.z;
}

// one 32 B record per edge: {a0..a3 | a4,a5,a6, src_bits}; slot = off[d] + rank[e]
__global__ void k_fill(const int* __restrict__ src, const int* __restrict__ dst,
                       const float* __restrict__ eattr, const int* __restrict__ off,
                       const int* __restrict__ rank, float* __restrict__ rec, int E) {
    int e = blockIdx.x * blockDim.x + threadIdx.x;
    if (e >= E) return;
    int slot = off[dst[e]] + rank[e];
    float a[7];
#pragma unroll
    for (int k = 0; k < 7; k++) a[k] = eattr[e * 7 + k];
    float4* rp = (float4*)(rec + (size_t)slot * 8);
    rp[0] = make_float4(a[0], a[1], a[2], a[3]);
    rp[1] = make_float4(a[4], a[5], a[6], __int_as_float(src[e]));
}

// ---------------- embedding gather (float4) ----------------
__global__ void k_embed(const int* __restrict__ x, const float* __restrict__ emb,
                        float* __restrict__ hcat, int N) {
    int idx = blockIdx.x * blockDim.x + threadIdx.x;
    int node = idx >> 4, j4 = (idx & 15) * 4;
    if (node < N) {
        float4 v = *(const float4*)(emb + (size_t)x[node] * 64 + j4);
        *(float4*)(hcat + (size_t)node * 256 + j4) = v;
    }
}

// ---------------- tiled fp32 GEMM: [N,64]@[64,64] (+bias,relu); fp32 or fp16 out --
__global__ __launch_bounds__(256) void k_gemm64(
    const float* __restrict__ A, int a_stride,
    const float* __restrict__ B, const float* __restrict__ bias,
    float* __restrict__ C, int c_stride, __half* __restrict__ Ch,
    int N, int do_relu,
    const float* __restrict__ ar, float* __restrict__ r_out)
{
    __shared__ __align__(16) float sA[64][132];
    __shared__ __align__(16) float sB[64 * 64];
    __shared__ float sar[64];
    int tid = threadIdx.x;
    int row0 = blockIdx.x * 128;

    {
        const float4* b4 = (const float4*)B;
        float4* s4 = (float4*)sB;
        for (int i = tid; i < 1024; i += 256) s4[i] = b4[i];
    }
    if (ar && tid < 64) sar[tid] = ar[tid];

#pragma unroll
    for (int pass = 0; pass < 8; ++pass) {
        int nl = pass * 16 + (tid & 15);
        int k4 = (tid >> 4) * 4;
        int n = row0 + nl; if (n >= N) n = N - 1;
        float4 v = *(const float4*)(A + (size_t)n * a_stride + k4);
        sA[k4 + 0][nl] = v.x; sA[k4 + 1][nl] = v.y;
        sA[k4 + 2][nl] = v.z; sA[k4 + 3][nl] = v.w;
    }
    __syncthreads();

    int tr = tid >> 4, tc = tid & 15;
    int r0 = tr * 8, c0 = tc * 4;
    float acc[8][4];
#pragma unroll
    for (int i = 0; i < 8; i++)
#pragma unroll
        for (int j = 0; j < 4; j++) acc[i][j] = 0.f;

#pragma unroll 4
    for (int k = 0; k < 64; ++k) {
        float4 b4 = *(const float4*)(sB + k * 64 + c0);
        float4 a0 = *(const float4*)&sA[k][r0];
        float4 a1 = *(const float4*)&sA[k][r0 + 4];
#pragma unroll
        for (int j = 0; j < 4; j++) {
            float bj = (&b4.x)[j];
            acc[0][j] += a0.x * bj; acc[1][j] += a0.y * bj;
            acc[2][j] += a0.z * bj; acc[3][j] += a0.w * bj;
            acc[4][j] += a1.x * bj; acc[5][j] += a1.y * bj;
            acc[6][j] += a1.z * bj; acc[7][j] += a1.w * bj;
        }
    }

    float4 bv = make_float4(0.f, 0.f, 0.f, 0.f);
    if (bias) bv = *(const float4*)(bias + c0);
#pragma unroll
    for (int i = 0; i < 8; i++) {
        int n = row0 + r0 + i;
        if (n < N) {
            float4 o;
            o.x = acc[i][0] + bv.x; o.y = acc[i][1] + bv.y;
            o.z = acc[i][2] + bv.z; o.w = acc[i][3] + bv.w;
            if (do_relu) {
                o.x = fmaxf(o.x, 0.f); o.y = fmaxf(o.y, 0.f);
                o.z = fmaxf(o.z, 0.f); o.w = fmaxf(o.w, 0.f);
            }
            if (C) *(float4*)(C + (size_t)n * c_stride + c0) = o;
            if (Ch) {
                __half2* hp = (__half2*)(Ch + (size_t)n * 64 + c0);
                hp[0] = __floats2half2_rn(o.x, o.y);
                hp[1] = __floats2half2_rn(o.z, o.w);
            }
        }
    }

    if (r_out && tid < 128) {
        int n = row0 + tid;
        if (n < N) {
            float racc = 0.f;
#pragma unroll
            for (int k = 0; k < 64; k++) racc += sA[k][tid] * sar[k];
            r_out[n] = racc;
        }
    }
}

// ---------------- gate conv: wave/node, 8 edges/iter, record prefetch, fp16 g ----
__global__ __launch_bounds__(256) void k_conv(
    const int* __restrict__ off, const float* __restrict__ rec,
    const __half* __restrict__ g, const float* __restrict__ r,
    const float* __restrict__ w1, const float* __restrict__ al,
    float* __restrict__ aggdst, int N)
{
    int lane = threadIdx.x & 63;
    int wid  = threadIdx.x >> 6;
    int node = blockIdx.x * 4 + wid;
    if (node >= N) return;                 // wave-uniform exit, no barriers
    int q = lane >> 4, l16 = lane & 15;

    float4 w1b[7];
#pragma unroll
    for (int k = 0; k < 7; k++)
        w1b[k] = *(const float4*)(w1 + (64 + k) * 64 + 4 * l16);
    float4 al4 = *(const float4*)(al + 4 * l16);
    float ri = r[node];
    int e0 = off[node], e1 = off[node + 1];

    float4 s = make_float4(0.f, 0.f, 0.f, 0.f);
    float den = 0.f;
    if (e0 < e1) {
        int ca = min(e0 + q, e1 - 1), cb = min(e0 + 4 + q, e1 - 1);
        const float4* rpa = (const float4*)(rec + (size_t)ca * 8);
        const float4* rpb = (const float4*)(rec + (size_t)cb * 8);
        float4 a0 = rpa[0], a1 = rpa[1];
        float4 b0 = rpb[0], b1 = rpb[1];
        for (int e = e0; e < e1; ) {       // trip condition wave-uniform
            bool va = (e + q) < e1, vb = (e + 4 + q) < e1;
            int sna = __float_as_int(a1.w), snb = __float_as_int(b1.w);
            // g gathers for current group (2 lines each, fp16)
            float4 ga = load_h4(g + (size_t)sna * 64 + 4 * l16);
            float4 gb = load_h4(g + (size_t)snb * 64 + 4 * l16);
            // prefetch next group's records (independent of ga/gb)
            int ne = e + 8;
            float4 na0 = a0, na1 = a1, nb0 = b0, nb1 = b1;
            if (ne < e1) {
                int nca = min(ne + q, e1 - 1), ncb = min(ne + 4 + q, e1 - 1);
                const float4* npa = (const float4*)(rec + (size_t)nca * 8);
                const float4* npb = (const float4*)(rec + (size_t)ncb * 8);
                na0 = npa[0]; na1 = npa[1];
                nb0 = npb[0]; nb1 = npb[1];
            }

            float4 cA;
            cA.x = a0.x*w1b[0].x + a0.y*w1b[1].x + a0.z*w1b[2].x + a0.w*w1b[3].x
                 + a1.x*w1b[4].x + a1.y*w1b[5].x + a1.z*w1b[6].x;
            cA.y = a0.x*w1b[0].y + a0.y*w1b[1].y + a0.z*w1b[2].y + a0.w*w1b[3].y
                 + a1.x*w1b[4].y + a1.y*w1b[5].y + a1.z*w1b[6].y;
            cA.z = a0.x*w1b[0].z + a0.y*w1b[1].z + a0.z*w1b[2].z + a0.w*w1b[3].z
                 + a1.x*w1b[4].z + a1.y*w1b[5].z + a1.z*w1b[6].z;
            cA.w = a0.x*w1b[0].w + a0.y*w1b[1].w + a0.z*w1b[2].w + a0.w*w1b[3].w
                 + a1.x*w1b[4].w + a1.y*w1b[5].w + a1.z*w1b[6].w;
            float4 cB;
            cB.x = b0.x*w1b[0].x + b0.y*w1b[1].x + b0.z*w1b[2].x + b0.w*w1b[3].x
                 + b1.x*w1b[4].x + b1.y*w1b[5].x + b1.z*w1b[6].x;
            cB.y = b0.x*w1b[0].y + b0.y*w1b[1].y + b0.z*w1b[2].y + b0.w*w1b[3].y
                 + b1.x*w1b[4].y + b1.y*w1b[5].y + b1.z*w1b[6].y;
            cB.z = b0.x*w1b[0].z + b0.y*w1b[1].z + b0.z*w1b[2].z + b0.w*w1b[3].z
                 + b1.x*w1b[4].z + b1.y*w1b[5].z + b1.z*w1b[6].z;
            cB.w = b0.x*w1b[0].w + b0.y*w1b[1].w + b0.z*w1b[2].w + b0.w*w1b[3].w
                 + b1.x*w1b[4].w + b1.y*w1b[5].w + b1.z*w1b[6].w;

            float4 xa, xb;
            xa.x = lrelu(ga.x + cA.x); xa.y = lrelu(ga.y + cA.y);
            xa.z = lrelu(ga.z + cA.z); xa.w = lrelu(ga.w + cA.w);
            xb.x = lrelu(gb.x + cB.x); xb.y = lrelu(gb.y + cB.y);
            xb.z = lrelu(gb.z + cB.z); xb.w = lrelu(gb.w + cB.w);
            float pa = xa.x*al4.x + xa.y*al4.y + xa.z*al4.z + xa.w*al4.w;
            float pb = xb.x*al4.x + xb.y*al4.y + xb.z*al4.z + xb.w*al4.w;
            pa = q16_allsum(pa);
            pb = q16_allsum(pb);
            float wa = va ? __expf(lrelu(pa + ri)) : 0.f;  // |alpha| bounded, no max-sub
            float wb = vb ? __expf(lrelu(pb + ri)) : 0.f;
            s.x += wa * xa.x + wb * xb.x;
            s.y += wa * xa.y + wb * xb.y;
            s.z += wa * xa.z + wb * xb.z;
            s.w += wa * xa.w + wb * xb.w;
            den += wa + wb;

            a0 = na0; a1 = na1; b0 = nb0; b1 = nb1;
            e = ne;
        }
    }
    s.x = x16_32_sum(s.x); s.y = x16_32_sum(s.y);
    s.z = x16_32_sum(s.z); s.w = x16_32_sum(s.w);
    den = x16_32_sum(den);
    float inv = 1.f / (den + 1e-16f);
    if (q == 0) {
        float4 o = make_float4(s.x * inv, s.y * inv, s.z * inv, s.w * inv);
        *(float4*)(aggdst + (size_t)node * 256 + 4 * l16) = o;
    }
}

// ---------------- head: fc1 + relu + fc2 + sigmoid ----------------
__global__ void k_head(const float* __restrict__ hcat, const float* __restrict__ f1w,
                       const float* __restrict__ f1b, const float* __restrict__ f2w,
                       const float* __restrict__ f2b, float* __restrict__ out, int N) {
    int i = blockIdx.x * blockDim.x + threadIdx.x;
    if (i >= N) return;
    float z[20];
#pragma unroll
    for (int j = 0; j < 20; j++) z[j] = f1b[j];
    const float4* hr = (const float4*)(hcat + (size_t)i * 256);
    for (int k4 = 0; k4 < 64; k4++) {
        float4 h = hr[k4];
        const float* wr = f1w + k4 * 4 * 20;
#pragma unroll
        for (int j = 0; j < 20; j++)
            z[j] += h.x * wr[j] + h.y * wr[20 + j] + h.z * wr[40 + j] + h.w * wr[60 + j];
    }
    float o = f2b[0];
#pragma unroll
    for (int j = 0; j < 20; j++) o += fmaxf(z[j], 0.f) * f2w[j];
    out[i] = 1.f / (1.f + __expf(-o));
}

extern "C" void kernel_launch(void* const* d_in, const int* in_sizes, int n_in,
                              void* d_out, int out_size, void* d_ws, size_t ws_size,
                              hipStream_t stream) {
    const int*   x     = (const int*)d_in[0];
    const int*   eidx  = (const int*)d_in[1];
    const float* eattr = (const float*)d_in[2];
    const float* emb   = (const float*)d_in[3];
    const float* lin1  = (const float*)d_in[4];   // [3,71,64]
    const float* attl  = (const float*)d_in[5];   // [3,64]
    const float* attr_ = (const float*)d_in[6];   // [3,64]
    const float* lin2  = (const float*)d_in[7];   // [3,64,64]
    const float* gbias = (const float*)d_in[8];   // [3,64]
    const float* f1w   = (const float*)d_in[9];   // [256,20]
    const float* f1b   = (const float*)d_in[10];
    const float* f2w   = (const float*)d_in[11];
    const float* f2b   = (const float*)d_in[12];
    float* out = (float*)d_out;

    int N = in_sizes[0];
    int E = in_sizes[1] / 2;
    const int* src = eidx;
    const int* dst = eidx + E;

    // workspace carve (256B aligned) — ~103 MB
    char* p = (char*)d_ws;
    auto alloc = [&](size_t bytes) { void* q = (void*)p; p += (bytes + 255) & ~(size_t)255; return q; };
    float*  hcat  = (float*)alloc((size_t)N * 256 * 4);
    __half* g     = (__half*)alloc((size_t)N * 64 * 2);
    float*  r     = (float*)alloc((size_t)N * 4);
    int*    off   = (int*)alloc((size_t)(N + 1) * 4);
    int*    deg   = (int*)alloc((size_t)N * 4);
    int*    rank  = (int*)alloc((size_t)E * 4);
    int*    bsum  = (int*)alloc(256 * 4);
    int*    bbase = (int*)alloc(256 * 4);
    float*  rec   = (float*)alloc((size_t)E * 8 * 4);   // 32 B/edge: attr + src

    int nb = (N + 1023) / 1024;   // 49 for N=50000 (<=256 required by k_scan_mid)

    k_zero<<<(N + 255) / 256, 256, 0, stream>>>(deg, N);
    k_count<<<(E + 255) / 256, 256, 0, stream>>>(dst, deg, rank, E);
    k_scan_part<<<nb, 256, 0, stream>>>(deg, bsum, N);
    k_scan_mid<<<1, 256, 0, stream>>>(bsum, bbase, off, nb, N);
    k_scan_out<<<nb, 256, 0, stream>>>(deg, bbase, off, N);
    k_fill<<<(E + 255) / 256, 256, 0, stream>>>(src, dst, eattr, off, rank, rec, E);
    k_embed<<<(N * 16 + 255) / 256, 256, 0, stream>>>(x, emb, hcat, N);

    int nbg = (N + 127) / 128;
    int nbc = (N + 3) / 4;
    for (int l = 0; l < 3; l++) {
        const float* w1l = lin1 + (size_t)l * 71 * 64;
        // g(fp16) = h_l @ W1a ; r = h_l . att_r
        k_gemm64<<<nbg, 256, 0, stream>>>(hcat + 64 * l, 256, w1l, nullptr,
                                          nullptr, 0, g, N, 0, attr_ + l * 64, r);
        k_conv<<<nbc, 256, 0, stream>>>(off, rec, g, r, w1l, attl + l * 64,
                                        hcat + 64 * (l + 1), N);
        // in-place fp32: hcat[:,l+1] = relu(agg @ W2 + b)
        k_gemm64<<<nbg, 256, 0, stream>>>(hcat + 64 * (l + 1), 256,
                                          lin2 + (size_t)l * 4096, gbias + l * 64,
                                          hcat + 64 * (l + 1), 256, nullptr, N, 1,
                                          nullptr, nullptr);
    }
    k_head<<<(N + 255) / 256, 256, 0, stream>>>(hcat, f1w, f1b, f2w, f2b, out, N);
}

// Round 5
// 537.825 us; speedup vs baseline: 2.0513x; 1.1752x over previous
//
#include <hip/hip_runtime.h>
#include <math.h>

#define NEG 0.01f

typedef _Float16 f16;
typedef f16 h2 __attribute__((ext_vector_type(2)));

__device__ __forceinline__ float lrelu(float x) { return x > 0.f ? x : NEG * x; }

__device__ __forceinline__ h2 lrelu2(h2 x) {
    h2 y = x * (f16)0.01f;                        // v_pk_mul_f16
    return __builtin_elementwise_max(x, y);       // v_pk_max_f16 (x<0 -> 0.01x)
}

// sum across each 16-lane row via DPP; result in all 16 lanes of the row
__device__ __forceinline__ float q16_allsum(float v) {
    int x;
    x = __builtin_amdgcn_update_dpp(0, __float_as_int(v), 0xB1, 0xF, 0xF, true);  v += __int_as_float(x); // quad_perm xor1
    x = __builtin_amdgcn_update_dpp(0, __float_as_int(v), 0x4E, 0xF, 0xF, true);  v += __int_as_float(x); // quad_perm xor2
    x = __builtin_amdgcn_update_dpp(0, __float_as_int(v), 0x124, 0xF, 0xF, true); v += __int_as_float(x); // row_ror:4
    x = __builtin_amdgcn_update_dpp(0, __float_as_int(v), 0x128, 0xF, 0xF, true); v += __int_as_float(x); // row_ror:8
    return v;
}

__device__ __forceinline__ float x16_32_sum(float v) {
    v += __int_as_float(__builtin_amdgcn_ds_swizzle(__float_as_int(v), 0x401F)); // xor 16
    v += __shfl_xor(v, 32, 64);
    return v;
}

// ---------------- CSR build ----------------
__global__ void k_zero(int* deg, int n) {
    int i = blockIdx.x * blockDim.x + threadIdx.x;
    if (i < n) deg[i] = 0;
}

__global__ void k_count(const int* __restrict__ dst, int* __restrict__ deg,
                        int* __restrict__ rank, int E) {
    int e = blockIdx.x * blockDim.x + threadIdx.x;
    if (e < E) rank[e] = atomicAdd(&deg[dst[e]], 1);
}

__global__ __launch_bounds__(256) void k_scan_part(const int* __restrict__ deg,
                                                   int* __restrict__ bsum, int n) {
    __shared__ int sh[256];
    int b = blockIdx.x, t = threadIdx.x;
    int i0 = b * 1024 + t * 4;
    int s = 0;
    if (i0 + 3 < n) { int4 v = *(const int4*)(deg + i0); s = v.x + v.y + v.z + v.w; }
    else { for (int k = 0; k < 4; k++) if (i0 + k < n) s += deg[i0 + k]; }
    sh[t] = s; __syncthreads();
    for (int d = 128; d > 0; d >>= 1) { if (t < d) sh[t] += sh[t + d]; __syncthreads(); }
    if (t == 0) bsum[b] = sh[0];
}

// every block redundantly scans bsum (nb<=256), then emits its 1024 offsets
__global__ __launch_bounds__(256) void k_scan_out(const int* __restrict__ deg,
                                                  const int* __restrict__ bsum,
                                                  int* __restrict__ off, int nb, int n) {
    __shared__ int sb[256];
    __shared__ int sh[256];
    int b = blockIdx.x, t = threadIdx.x;
    int v = (t < nb) ? bsum[t] : 0;
    sb[t] = v; __syncthreads();
    for (int d = 1; d < 256; d <<= 1) {
        int u = (t >= d) ? sb[t - d] : 0;
        __syncthreads(); sb[t] += u; __syncthreads();
    }
    int base = (b == 0) ? 0 : sb[b - 1];
    if (b == 0 && t == 0) off[n] = sb[255];
    int i0 = b * 1024 + t * 4;
    int4 v4 = make_int4(0, 0, 0, 0);
    if (i0 + 3 < n) v4 = *(const int4*)(deg + i0);
    else {
        v4.x = (i0     < n) ? deg[i0]     : 0;
        v4.y = (i0 + 1 < n) ? deg[i0 + 1] : 0;
        v4.z = (i0 + 2 < n) ? deg[i0 + 2] : 0;
        v4.w = (i0 + 3 < n) ? deg[i0 + 3] : 0;
    }
    int s = v4.x + v4.y + v4.z + v4.w;
    sh[t] = s; __syncthreads();
    for (int d = 1; d < 256; d <<= 1) {
        int u = (t >= d) ? sh[t - d] : 0;
        __syncthreads(); sh[t] += u; __syncthreads();
    }
    int ex = base + sh[t] - s;
    if (i0     < n) off[i0]     = ex;
    if (i0 + 1 < n) off[i0 + 1] = ex + v4.x;
    if (i0 + 2 < n) off[i0 + 2] = ex + v4.x + v4.y;
    if (i0 + 3 < n) off[i0 + 3] = ex + v4.x + v4.y + v4.z;
}

// fused: blocks [0,nbE) build 16B fp16 edge records; blocks [nbE,..) do embed gather
__global__ void k_fill_embed(const int* __restrict__ src, const int* __restrict__ dst,
                             const float* __restrict__ eattr, const int* __restrict__ off,
                             const int* __restrict__ rank, uint4* __restrict__ rec, int E,
                             int nbE,
                             const int* __restrict__ x, const float* __restrict__ emb,
                             float* __restrict__ hcat, int N) {
    if ((int)blockIdx.x < nbE) {
        int e = blockIdx.x * 256 + threadIdx.x;
        if (e >= E) return;
        int slot = off[dst[e]] + rank[e];
        const float* ap = eattr + (size_t)e * 7;
        float a0 = ap[0], a1 = ap[1], a2 = ap[2], a3 = ap[3], a4 = ap[4], a5 = ap[5], a6 = ap[6];
        uint4 rv;
        h2 p01 = { (f16)a0, (f16)a1 };
        h2 p23 = { (f16)a2, (f16)a3 };
        h2 p45 = { (f16)a4, (f16)a5 };
        rv.x = __builtin_bit_cast(unsigned int, p01);
        rv.y = __builtin_bit_cast(unsigned int, p23);
        rv.z = __builtin_bit_cast(unsigned int, p45);
        unsigned int a6b = (unsigned int)__builtin_bit_cast(unsigned short, (f16)a6);
        rv.w = a6b | ((unsigned int)src[e] << 16);   // requires N < 65536
        rec[slot] = rv;
    } else {
        int idx = ((int)blockIdx.x - nbE) * 256 + threadIdx.x;
        int node = idx >> 4, j4 = (idx & 15) * 4;
        if (node < N) {
            float4 v = *(const float4*)(emb + (size_t)x[node] * 64 + j4);
            *(float4*)(hcat + (size_t)node * 256 + j4) = v;
        }
    }
}

// ---------------- tiled fp32 GEMM: [N,64]@[64,64] (+bias,relu); fp32 or fp16 out --
__global__ __launch_bounds__(256) void k_gemm64(
    const float* __restrict__ A, int a_stride,
    const float* __restrict__ B, const float* __restrict__ bias,
    float* __restrict__ C, int c_stride, f16* __restrict__ Ch,
    int N, int do_relu,
    const float* __restrict__ ar, float* __restrict__ r_out)
{
    __shared__ __align__(16) float sA[64][132];
    __shared__ __align__(16) float sB[64 * 64];
    __shared__ float sar[64];
    int tid = threadIdx.x;
    int row0 = blockIdx.x * 128;

    {
        const float4* b4 = (const float4*)B;
        float4* s4 = (float4*)sB;
        for (int i = tid; i < 1024; i += 256) s4[i] = b4[i];
    }
    if (ar && tid < 64) sar[tid] = ar[tid];

#pragma unroll
    for (int pass = 0; pass < 8; ++pass) {
        int nl = pass * 16 + (tid & 15);
        int k4 = (tid >> 4) * 4;
        int n = row0 + nl; if (n >= N) n = N - 1;
        float4 v = *(const float4*)(A + (size_t)n * a_stride + k4);
        sA[k4 + 0][nl] = v.x; sA[k4 + 1][nl] = v.y;
        sA[k4 + 2][nl] = v.z; sA[k4 + 3][nl] = v.w;
    }
    __syncthreads();

    int tr = tid >> 4, tc = tid & 15;
    int r0 = tr * 8, c0 = tc * 4;
    float acc[8][4];
#pragma unroll
    for (int i = 0; i < 8; i++)
#pragma unroll
        for (int j = 0; j < 4; j++) acc[i][j] = 0.f;

#pragma unroll 4
    for (int k = 0; k < 64; ++k) {
        float4 b4 = *(const float4*)(sB + k * 64 + c0);
        float4 a0 = *(const float4*)&sA[k][r0];
        float4 a1 = *(const float4*)&sA[k][r0 + 4];
#pragma unroll
        for (int j = 0; j < 4; j++) {
            float bj = (&b4.x)[j];
            acc[0][j] += a0.x * bj; acc[1][j] += a0.y * bj;
            acc[2][j] += a0.z * bj; acc[3][j] += a0.w * bj;
            acc[4][j] += a1.x * bj; acc[5][j] += a1.y * bj;
            acc[6][j] += a1.z * bj; acc[7][j] += a1.w * bj;
        }
    }

    float4 bv = make_float4(0.f, 0.f, 0.f, 0.f);
    if (bias) bv = *(const float4*)(bias + c0);
#pragma unroll
    for (int i = 0; i < 8; i++) {
        int n = row0 + r0 + i;
        if (n < N) {
            float4 o;
            o.x = acc[i][0] + bv.x; o.y = acc[i][1] + bv.y;
            o.z = acc[i][2] + bv.z; o.w = acc[i][3] + bv.w;
            if (do_relu) {
                o.x = fmaxf(o.x, 0.f); o.y = fmaxf(o.y, 0.f);
                o.z = fmaxf(o.z, 0.f); o.w = fmaxf(o.w, 0.f);
            }
            if (C) *(float4*)(C + (size_t)n * c_stride + c0) = o;
            if (Ch) {
                uint2 gw;
                gw.x = __builtin_bit_cast(unsigned int, __builtin_amdgcn_cvt_pkrtz(o.x, o.y));
                gw.y = __builtin_bit_cast(unsigned int, __builtin_amdgcn_cvt_pkrtz(o.z, o.w));
                *(uint2*)(Ch + (size_t)n * 64 + c0) = gw;
            }
        }
    }

    if (r_out && tid < 128) {
        int n = row0 + tid;
        if (n < N) {
            float racc = 0.f;
#pragma unroll
            for (int k = 0; k < 64; k++) racc += sA[k][tid] * sar[k];
            r_out[n] = racc;
        }
    }
}

// fused gemm2(layer l) + gemm1(layer l+1):
//   out1 = relu(agg@W2 + b) -> hc (in-place, stride 256)
//   g    = out1@W1n (fp16),  r = out1 . arn
__global__ __launch_bounds__(256) void k_gemm2g1(
    float* __restrict__ hc,
    const float* __restrict__ W2, const float* __restrict__ bias,
    const float* __restrict__ W1n, const float* __restrict__ arn,
    f16* __restrict__ g, float* __restrict__ r_out, int N)
{
    __shared__ __align__(16) float sA[64][132];
    __shared__ __align__(16) float sB[64 * 64];
    __shared__ float sar[64];
    int tid = threadIdx.x, row0 = blockIdx.x * 128;

    {
        const float4* b4 = (const float4*)W2;
        float4* s4 = (float4*)sB;
        for (int i = tid; i < 1024; i += 256) s4[i] = b4[i];
    }
    if (tid < 64) sar[tid] = arn[tid];

#pragma unroll
    for (int pass = 0; pass < 8; ++pass) {
        int nl = pass * 16 + (tid & 15);
        int k4 = (tid >> 4) * 4;
        int n = row0 + nl; if (n >= N) n = N - 1;
        float4 v = *(const float4*)(hc + (size_t)n * 256 + k4);
        sA[k4 + 0][nl] = v.x; sA[k4 + 1][nl] = v.y;
        sA[k4 + 2][nl] = v.z; sA[k4 + 3][nl] = v.w;
    }
    __syncthreads();

    int tr = tid >> 4, tc = tid & 15;
    int r0 = tr * 8, c0 = tc * 4;
    float acc[8][4];
#pragma unroll
    for (int i = 0; i < 8; i++)
#pragma unroll
        for (int j = 0; j < 4; j++) acc[i][j] = 0.f;

#pragma unroll 4
    for (int k = 0; k < 64; ++k) {
        float4 b4 = *(const float4*)(sB + k * 64 + c0);
        float4 a0 = *(const float4*)&sA[k][r0];
        float4 a1 = *(const float4*)&sA[k][r0 + 4];
#pragma unroll
        for (int j = 0; j < 4; j++) {
            float bj = (&b4.x)[j];
            acc[0][j] += a0.x * bj; acc[1][j] += a0.y * bj;
            acc[2][j] += a0.z * bj; acc[3][j] += a0.w * bj;
            acc[4][j] += a1.x * bj; acc[5][j] += a1.y * bj;
            acc[6][j] += a1.z * bj; acc[7][j] += a1.w * bj;
        }
    }

    float4 bv = *(const float4*)(bias + c0);
#pragma unroll
    for (int i = 0; i < 8; i++) {
        acc[i][0] = fmaxf(acc[i][0] + bv.x, 0.f);
        acc[i][1] = fmaxf(acc[i][1] + bv.y, 0.f);
        acc[i][2] = fmaxf(acc[i][2] + bv.z, 0.f);
        acc[i][3] = fmaxf(acc[i][3] + bv.w, 0.f);
        int n = row0 + r0 + i;
        if (n < N) *(float4*)(hc + (size_t)n * 256 + c0) =
            make_float4(acc[i][0], acc[i][1], acc[i][2], acc[i][3]);
    }
    __syncthreads();   // everyone done reading sA/sB

    // restage: sB <- W1n, sA <- out1^T
    {
        const float4* b4 = (const float4*)W1n;
        float4* s4 = (float4*)sB;
        for (int i = tid; i < 1024; i += 256) s4[i] = b4[i];
    }
#pragma unroll
    for (int i = 0; i < 8; i++)
#pragma unroll
        for (int j = 0; j < 4; j++) sA[c0 + j][r0 + i] = acc[i][j];
    __syncthreads();

#pragma unroll
    for (int i = 0; i < 8; i++)
#pragma unroll
        for (int j = 0; j < 4; j++) acc[i][j] = 0.f;

#pragma unroll 4
    for (int k = 0; k < 64; ++k) {
        float4 b4 = *(const float4*)(sB + k * 64 + c0);
        float4 a0 = *(const float4*)&sA[k][r0];
        float4 a1 = *(const float4*)&sA[k][r0 + 4];
#pragma unroll
        for (int j = 0; j < 4; j++) {
            float bj = (&b4.x)[j];
            acc[0][j] += a0.x * bj; acc[1][j] += a0.y * bj;
            acc[2][j] += a0.z * bj; acc[3][j] += a0.w * bj;
            acc[4][j] += a1.x * bj; acc[5][j] += a1.y * bj;
            acc[6][j] += a1.z * bj; acc[7][j] += a1.w * bj;
        }
    }

#pragma unroll
    for (int i = 0; i < 8; i++) {
        int n = row0 + r0 + i;
        if (n < N) {
            uint2 gw;
            gw.x = __builtin_bit_cast(unsigned int, __builtin_amdgcn_cvt_pkrtz(acc[i][0], acc[i][1]));
            gw.y = __builtin_bit_cast(unsigned int, __builtin_amdgcn_cvt_pkrtz(acc[i][2], acc[i][3]));
            *(uint2*)(g + (size_t)n * 64 + c0) = gw;
        }
    }
    if (tid < 128) {
        int n = row0 + tid;
        if (n < N) {
            float racc = 0.f;
#pragma unroll
            for (int k = 0; k < 64; k++) racc += sA[k][tid] * sar[k];
            r_out[n] = racc;
        }
    }
}

// ---------------- gate conv: wave/node, 8 edges/iter, fdot2 fp16 math ----
struct ConvW {
    h2 w01[4], w23[4], w45[4], w6_[4];
    h2 al01, al23;
};

__device__ __forceinline__ void do_edge(uint4 rv, bool valid, float ri,
                                        const ConvW& W, const f16* __restrict__ g,
                                        int l16, float4& s, float& den) {
    h2 a01 = __builtin_bit_cast(h2, rv.x);
    h2 a23 = __builtin_bit_cast(h2, rv.y);
    h2 a45 = __builtin_bit_cast(h2, rv.z);
    h2 a6p = __builtin_bit_cast(h2, rv.w & 0xFFFFu);   // (a6, +0)
    int sn  = (int)(rv.w >> 16);
    uint2 gv = *(const uint2*)(g + (size_t)sn * 64 + 4 * l16);
    h2 g01 = __builtin_bit_cast(h2, gv.x);
    h2 g23 = __builtin_bit_cast(h2, gv.y);

    float c0 = __builtin_amdgcn_fdot2(a01, W.w01[0],
               __builtin_amdgcn_fdot2(a23, W.w23[0],
               __builtin_amdgcn_fdot2(a45, W.w45[0],
               __builtin_amdgcn_fdot2(a6p, W.w6_[0], 0.f, false), false), false), false);
    float c1 = __builtin_amdgcn_fdot2(a01, W.w01[1],
               __builtin_amdgcn_fdot2(a23, W.w23[1],
               __builtin_amdgcn_fdot2(a45, W.w45[1],
               __builtin_amdgcn_fdot2(a6p, W.w6_[1], 0.f, false), false), false), false);
    float c2 = __builtin_amdgcn_fdot2(a01, W.w01[2],
               __builtin_amdgcn_fdot2(a23, W.w23[2],
               __builtin_amdgcn_fdot2(a45, W.w45[2],
               __builtin_amdgcn_fdot2(a6p, W.w6_[2], 0.f, false), false), false), false);
    float c3 = __builtin_amdgcn_fdot2(a01, W.w01[3],
               __builtin_amdgcn_fdot2(a23, W.w23[3],
               __builtin_amdgcn_fdot2(a45, W.w45[3],
               __builtin_amdgcn_fdot2(a6p, W.w6_[3], 0.f, false), false), false), false);

    h2 x01 = lrelu2(g01 + __builtin_amdgcn_cvt_pkrtz(c0, c1));
    h2 x23 = lrelu2(g23 + __builtin_amdgcn_cvt_pkrtz(c2, c3));
    float p = __builtin_amdgcn_fdot2(x01, W.al01,
              __builtin_amdgcn_fdot2(x23, W.al23, 0.f, false), false);
    p = q16_allsum(p);
    float alpha = lrelu(p + ri);
    float w = valid ? __expf(alpha) : 0.f;   // |alpha| bounded: no max-subtraction
    s.x += w * (float)x01.x; s.y += w * (float)x01.y;
    s.z += w * (float)x23.x; s.w += w * (float)x23.y;
    den += w;
}

__global__ __launch_bounds__(256) void k_conv(
    const int* __restrict__ off, const uint4* __restrict__ rec,
    const f16* __restrict__ g, const float* __restrict__ r,
    const float* __restrict__ w1, const float* __restrict__ al,
    float* __restrict__ aggdst, int N)
{
    int lane = threadIdx.x & 63;
    int wid  = threadIdx.x >> 6;
    int node = blockIdx.x * 4 + wid;
    if (node >= N) return;                 // wave-uniform exit, no barriers
    int q = lane >> 4, l16 = lane & 15;

    ConvW W;
    const float* wb = w1 + 64 * 64;        // rows 64..70 of lin1
#pragma unroll
    for (int j = 0; j < 4; j++) {
        int f = 4 * l16 + j;
        W.w01[j] = h2{ (f16)wb[f],       (f16)wb[64 + f]  };
        W.w23[j] = h2{ (f16)wb[128 + f], (f16)wb[192 + f] };
        W.w45[j] = h2{ (f16)wb[256 + f], (f16)wb[320 + f] };
        W.w6_[j] = h2{ (f16)wb[384 + f], (f16)0.f         };
    }
    W.al01 = h2{ (f16)al[4 * l16],     (f16)al[4 * l16 + 1] };
    W.al23 = h2{ (f16)al[4 * l16 + 2], (f16)al[4 * l16 + 3] };

    float ri = r[node];
    int e0 = off[node], e1 = off[node + 1];

    float4 s = make_float4(0.f, 0.f, 0.f, 0.f);
    float den = 0.f;
    for (int e = e0; e < e1; e += 8) {
        int ea = e + q, eb = e + 4 + q;
        bool va = ea < e1, vb = eb < e1;
        uint4 ra = rec[va ? ea : (e1 - 1)];
        uint4 rb = rec[vb ? eb : (e1 - 1)];
        do_edge(ra, va, ri, W, g, l16, s, den);
        do_edge(rb, vb, ri, W, g, l16, s, den);
    }
    s.x = x16_32_sum(s.x); s.y = x16_32_sum(s.y);
    s.z = x16_32_sum(s.z); s.w = x16_32_sum(s.w);
    den = x16_32_sum(den);
    float inv = 1.f / (den + 1e-16f);
    if (q == 0) {
        float4 o = make_float4(s.x * inv, s.y * inv, s.z * inv, s.w * inv);
        *(float4*)(aggdst + (size_t)node * 256 + 4 * l16) = o;
    }
}

// ---------------- head: fc1 + relu + fc2 + sigmoid ----------------
__global__ void k_head(const float* __restrict__ hcat, const float* __restrict__ f1w,
                       const float* __restrict__ f1b, const float* __restrict__ f2w,
                       const float* __restrict__ f2b, float* __restrict__ out, int N) {
    int i = blockIdx.x * blockDim.x + threadIdx.x;
    if (i >= N) return;
    float z[20];
#pragma unroll
    for (int j = 0; j < 20; j++) z[j] = f1b[j];
    const float4* hr = (const float4*)(hcat + (size_t)i * 256);
    for (int k4 = 0; k4 < 64; k4++) {
        float4 h = hr[k4];
        const float* wr = f1w + k4 * 4 * 20;
#pragma unroll
        for (int j = 0; j < 20; j++)
            z[j] += h.x * wr[j] + h.y * wr[20 + j] + h.z * wr[40 + j] + h.w * wr[60 + j];
    }
    float o = f2b[0];
#pragma unroll
    for (int j = 0; j < 20; j++) o += fmaxf(z[j], 0.f) * f2w[j];
    out[i] = 1.f / (1.f + __expf(-o));
}

extern "C" void kernel_launch(void* const* d_in, const int* in_sizes, int n_in,
                              void* d_out, int out_size, void* d_ws, size_t ws_size,
                              hipStream_t stream) {
    const int*   x     = (const int*)d_in[0];
    const int*   eidx  = (const int*)d_in[1];
    const float* eattr = (const float*)d_in[2];
    const float* emb   = (const float*)d_in[3];
    const float* lin1  = (const float*)d_in[4];   // [3,71,64]
    const float* attl  = (const float*)d_in[5];   // [3,64]
    const float* attr_ = (const float*)d_in[6];   // [3,64]
    const float* lin2  = (const float*)d_in[7];   // [3,64,64]
    const float* gbias = (const float*)d_in[8];   // [3,64]
    const float* f1w   = (const float*)d_in[9];   // [256,20]
    const float* f1b   = (const float*)d_in[10];
    const float* f2w   = (const float*)d_in[11];
    const float* f2b   = (const float*)d_in[12];
    float* out = (float*)d_out;

    int N = in_sizes[0];
    int E = in_sizes[1] / 2;
    const int* src = eidx;
    const int* dst = eidx + E;

    // workspace carve (256B aligned) — ~83 MB
    char* p = (char*)d_ws;
    auto alloc = [&](size_t bytes) { void* q = (void*)p; p += (bytes + 255) & ~(size_t)255; return q; };
    float* hcat = (float*)alloc((size_t)N * 256 * 4);
    f16*   g    = (f16*)alloc((size_t)N * 64 * 2);
    float* r    = (float*)alloc((size_t)N * 4);
    int*   off  = (int*)alloc((size_t)(N + 1) * 4);
    int*   deg  = (int*)alloc((size_t)N * 4);
    int*   rank = (int*)alloc((size_t)E * 4);
    int*   bsum = (int*)alloc(256 * 4);
    uint4* rec  = (uint4*)alloc((size_t)E * 16);   // 16 B/edge: fp16 attrs + u16 src

    int nbs = (N + 1023) / 1024;     // 49 scan blocks (<=256)
    int nbE = (E + 255) / 256;
    int nbEmb = (N * 16 + 255) / 256;

    k_zero<<<(N + 255) / 256, 256, 0, stream>>>(deg, N);
    k_count<<<nbE, 256, 0, stream>>>(dst, deg, rank, E);
    k_scan_part<<<nbs, 256, 0, stream>>>(deg, bsum, N);
    k_scan_out<<<nbs, 256, 0, stream>>>(deg, bsum, off, nbs, N);
    k_fill_embed<<<nbE + nbEmb, 256, 0, stream>>>(src, dst, eattr, off, rank, rec, E,
                                                  nbE, x, emb, hcat, N);

    int nbg = (N + 127) / 128;
    int nbc = (N + 3) / 4;
    // layer 0: g/r from embeddings
    k_gemm64<<<nbg, 256, 0, stream>>>(hcat, 256, lin1, nullptr,
                                      nullptr, 0, g, N, 0, attr_, r);
    k_conv<<<nbc, 256, 0, stream>>>(off, rec, g, r, lin1, attl, hcat + 64, N);
    // layer boundary 0->1 and 1->2: fused gemm2 + gemm1(next)
    for (int l = 0; l < 2; l++) {
        k_gemm2g1<<<nbg, 256, 0, stream>>>(hcat + 64 * (l + 1),
                                           lin2 + (size_t)l * 4096, gbias + l * 64,
                                           lin1 + (size_t)(l + 1) * 71 * 64,
                                           attr_ + (l + 1) * 64, g, r, N);
        k_conv<<<nbc, 256, 0, stream>>>(off, rec, g, r,
                                        lin1 + (size_t)(l + 1) * 71 * 64,
                                        attl + (l + 1) * 64, hcat + 64 * (l + 2), N);
    }
    // final gemm2 (layer 2) -> hcat col block 3
    k_gemm64<<<nbg, 256, 0, stream>>>(hcat + 192, 256, lin2 + 2 * 4096, gbias + 128,
                                      hcat + 192, 256, nullptr, N, 1, nullptr, nullptr);
    k_head<<<(N + 255) / 256, 256, 0, stream>>>(hcat, f1w, f1b, f2w, f2b, out, N);
}